// Round 1
// baseline (1999.410 us; speedup 1.0000x reference)
//
#include <hip/hip_runtime.h>

// ---------------- problem constants ----------------
#define B_    64
#define TOK_  576
#define DIM_  1024
#define TXT_  512
#define NT_   1000
#define NTP_  1024
#define H_    24
#define BT_   (B_ * TOK_)          // 36864 rows
static constexpr float SCALE_ = 0.0441941738241592f;   // 512^-0.5

typedef __bf16 bf16x8 __attribute__((ext_vector_type(8)));
typedef float  f32x4  __attribute__((ext_vector_type(4)));

__device__ __forceinline__ unsigned short f2bf(float f) {
    unsigned u = __float_as_uint(f);
    u += 0x7fffu + ((u >> 16) & 1u);
    return (unsigned short)(u >> 16);
}
__device__ __forceinline__ float bf2f(unsigned short h) {
    return __uint_as_float(((unsigned)h) << 16);
}
__device__ __forceinline__ f32x4 mfma16(bf16x8 a, bf16x8 b, f32x4 c) {
    return __builtin_amdgcn_mfma_f32_16x16x32_bf16(a, b, c, 0, 0, 0);
}
__device__ __forceinline__ void unpack8(uint4 v, float* f) {
    unsigned a0 = v.x, a1 = v.y, a2 = v.z, a3 = v.w;
    f[0] = bf2f((unsigned short)(a0 & 0xffff)); f[1] = bf2f((unsigned short)(a0 >> 16));
    f[2] = bf2f((unsigned short)(a1 & 0xffff)); f[3] = bf2f((unsigned short)(a1 >> 16));
    f[4] = bf2f((unsigned short)(a2 & 0xffff)); f[5] = bf2f((unsigned short)(a2 >> 16));
    f[6] = bf2f((unsigned short)(a3 & 0xffff)); f[7] = bf2f((unsigned short)(a3 >> 16));
}

// ---------------- weight prep ----------------
// Wq (1024x512 f32) -> WqT bf16 [branch][512][1024]  (tiled transpose)
__global__ void k_prep_wq(const float* __restrict__ wq1, const float* __restrict__ wq2,
                          unsigned short* __restrict__ wqt) {
    __shared__ float tile[64][68];
    int bx = blockIdx.x, t = threadIdx.x;
    int br = bx >> 7, kt = (bx >> 3) & 15, nt = bx & 7;
    const float* wq = br ? wq2 : wq1;
#pragma unroll
    for (int i = 0; i < 4; ++i) {
        int idx4 = t + i * 256;
        int kl = idx4 >> 4, n4 = (idx4 & 15) * 4;
        float4 v = *reinterpret_cast<const float4*>(wq + (size_t)(kt * 64 + kl) * 512 + nt * 64 + n4);
        tile[kl][n4 + 0] = v.x; tile[kl][n4 + 1] = v.y; tile[kl][n4 + 2] = v.z; tile[kl][n4 + 3] = v.w;
    }
    __syncthreads();
#pragma unroll
    for (int i = 0; i < 4; ++i) {
        int idx4 = t + i * 256;
        int nl = idx4 >> 4, k4 = (idx4 & 15) * 4;
        ushort4 o = make_ushort4(f2bf(tile[k4 + 0][nl]), f2bf(tile[k4 + 1][nl]),
                                 f2bf(tile[k4 + 2][nl]), f2bf(tile[k4 + 3][nl]));
        *reinterpret_cast<ushort4*>(wqt + (size_t)br * 512 * 1024 + (size_t)(nt * 64 + nl) * 1024 + kt * 64 + k4) = o;
    }
}

__global__ void k_f2bf(const float* __restrict__ src, unsigned short* __restrict__ dst, int n4) {
    int i = blockIdx.x * blockDim.x + threadIdx.x;
    if (i < n4) {
        float4 v = *reinterpret_cast<const float4*>(src + (size_t)i * 4);
        ushort4 o = make_ushort4(f2bf(v.x), f2bf(v.y), f2bf(v.z), f2bf(v.w));
        *reinterpret_cast<ushort4*>(dst + (size_t)i * 4) = o;
    }
}

// ---------------- kv layernorm:  text_fea (NT,B,TXT) -> kvn bf16 [b][n][e] ----------------
__global__ void k_kvln(const float* __restrict__ tf, const float* __restrict__ g,
                       const float* __restrict__ bta, unsigned short* __restrict__ kvn) {
    int row = blockIdx.x;                 // b*NT + n
    int b = row / NT_, n = row - b * NT_;
    const float* src = tf + ((size_t)n * B_ + b) * TXT_;
    int t = threadIdx.x;                  // 128 threads, 4 floats each
    float4 v = *reinterpret_cast<const float4*>(src + t * 4);
    float s = v.x + v.y + v.z + v.w;
    float ss = v.x * v.x + v.y * v.y + v.z * v.z + v.w * v.w;
#pragma unroll
    for (int d = 1; d < 64; d <<= 1) { s += __shfl_xor(s, d); ss += __shfl_xor(ss, d); }
    __shared__ float red[4];
    if ((t & 63) == 0) { red[(t >> 6) * 2] = s; red[(t >> 6) * 2 + 1] = ss; }
    __syncthreads();
    s = red[0] + red[2]; ss = red[1] + red[3];
    float m = s * (1.f / TXT_);
    float rs = rsqrtf(ss * (1.f / TXT_) - m * m + 1e-5f);
    int d0 = t * 4;
    ushort4 o = make_ushort4(f2bf((v.x - m) * rs * g[d0 + 0] + bta[d0 + 0]),
                             f2bf((v.y - m) * rs * g[d0 + 1] + bta[d0 + 1]),
                             f2bf((v.z - m) * rs * g[d0 + 2] + bta[d0 + 2]),
                             f2bf((v.w - m) * rs * g[d0 + 3] + bta[d0 + 3]));
    *reinterpret_cast<ushort4*>(kvn + ((size_t)b * NT_ + n) * TXT_ + d0) = o;
}

// ---------------- kv transpose:  kvn [b][n][e] -> kvt [b][e][n_pad1024] (zeros for n>=1000) ----------------
__global__ void k_kvt(const unsigned short* __restrict__ kvn, unsigned short* __restrict__ kvt) {
    __shared__ unsigned short tile[64][68];
    int bx = blockIdx.x;
    int b = bx >> 7, rem = bx & 127, et = rem >> 4, nt = rem & 15;
    int t = threadIdx.x;
#pragma unroll
    for (int i = 0; i < 4; ++i) {
        int idx4 = t + i * 256;
        int nl = idx4 >> 4, e4 = (idx4 & 15) * 4;
        int ng = nt * 64 + nl;
        ushort4 v = make_ushort4(0, 0, 0, 0);
        if (ng < NT_) v = *reinterpret_cast<const ushort4*>(kvn + ((size_t)b * NT_ + ng) * TXT_ + et * 64 + e4);
        tile[nl][e4 + 0] = v.x; tile[nl][e4 + 1] = v.y; tile[nl][e4 + 2] = v.z; tile[nl][e4 + 3] = v.w;
    }
    __syncthreads();
#pragma unroll
    for (int i = 0; i < 4; ++i) {
        int idx4 = t + i * 256;
        int el = idx4 >> 4, n4 = (idx4 & 15) * 4;
        ushort4 o = make_ushort4(tile[n4 + 0][el], tile[n4 + 1][el], tile[n4 + 2][el], tile[n4 + 3][el]);
        *reinterpret_cast<ushort4*>(kvt + ((size_t)b * TXT_ + et * 64 + el) * NTP_ + nt * 64 + n4) = o;
    }
}

// ---------------- x layernorm (both branches, shared stats) ----------------
__global__ void k_xln(const float* __restrict__ x,
                      const float* __restrict__ g1, const float* __restrict__ b1,
                      const float* __restrict__ g2, const float* __restrict__ b2,
                      unsigned short* __restrict__ xln) {
    int bt = blockIdx.x;                   // b*TOK + t
    int b = bt / TOK_, tk = bt - b * TOK_;
    const float* src = x + ((size_t)(tk + 1) * B_ + b) * DIM_;
    int t = threadIdx.x;                   // 256 threads, 4 floats each
    float4 v = *reinterpret_cast<const float4*>(src + t * 4);
    float s = v.x + v.y + v.z + v.w;
    float ss = v.x * v.x + v.y * v.y + v.z * v.z + v.w * v.w;
#pragma unroll
    for (int d = 1; d < 64; d <<= 1) { s += __shfl_xor(s, d); ss += __shfl_xor(ss, d); }
    __shared__ float red[8];
    if ((t & 63) == 0) { red[t >> 6] = s; red[4 + (t >> 6)] = ss; }
    __syncthreads();
    s = red[0] + red[1] + red[2] + red[3];
    ss = red[4] + red[5] + red[6] + red[7];
    float m = s * (1.f / DIM_);
    float rs = rsqrtf(ss * (1.f / DIM_) - m * m + 1e-5f);
    int d0 = t * 4;
    float c0 = (v.x - m) * rs, c1 = (v.y - m) * rs, c2 = (v.z - m) * rs, c3 = (v.w - m) * rs;
    ushort4 o1 = make_ushort4(f2bf(c0 * g1[d0 + 0] + b1[d0 + 0]), f2bf(c1 * g1[d0 + 1] + b1[d0 + 1]),
                              f2bf(c2 * g1[d0 + 2] + b1[d0 + 2]), f2bf(c3 * g1[d0 + 3] + b1[d0 + 3]));
    *reinterpret_cast<ushort4*>(xln + (size_t)bt * DIM_ + d0) = o1;
    ushort4 o2 = make_ushort4(f2bf(c0 * g2[d0 + 0] + b2[d0 + 0]), f2bf(c1 * g2[d0 + 1] + b2[d0 + 1]),
                              f2bf(c2 * g2[d0 + 2] + b2[d0 + 2]), f2bf(c3 * g2[d0 + 3] + b2[d0 + 3]));
    *reinterpret_cast<ushort4*>(xln + (size_t)BT_ * DIM_ + (size_t)bt * DIM_ + d0) = o2;
}

// ---------------- shared 128x128xK bf16 GEMM mainloop (A:[M][K], B:[N][K] both k-contig) ----------------
__device__ __forceinline__ void gemm_loop(const unsigned short* __restrict__ A,
                                          const unsigned short* __restrict__ Bp,
                                          int K, unsigned short* a_lds, unsigned short* b_lds,
                                          int tid, f32x4 acc[4][4]) {
    const int l = tid & 63, w = tid >> 6;
    const int l16 = l & 15, lg = l >> 4;
    const int wm = w & 1, wn = w >> 1;
    const f32x4 fz = {0.f, 0.f, 0.f, 0.f};
#pragma unroll
    for (int mt = 0; mt < 4; ++mt)
#pragma unroll
        for (int nt = 0; nt < 4; ++nt) acc[mt][nt] = fz;
    int nk = K >> 6;
    uint4 av[4], bv[4];
#pragma unroll
    for (int i = 0; i < 4; ++i) {
        int g = tid + i * 256, row = g >> 3, k8 = g & 7;
        av[i] = *reinterpret_cast<const uint4*>(A + (size_t)row * K + k8 * 8);
        bv[i] = *reinterpret_cast<const uint4*>(Bp + (size_t)row * K + k8 * 8);
    }
    for (int kt = 0; kt < nk; ++kt) {
#pragma unroll
        for (int i = 0; i < 4; ++i) {
            int g = tid + i * 256, row = g >> 3, k8 = g & 7;
            int k8s = k8 ^ (row & 7);
            *reinterpret_cast<uint4*>(a_lds + row * 64 + k8s * 8) = av[i];
            *reinterpret_cast<uint4*>(b_lds + row * 64 + k8s * 8) = bv[i];
        }
        __syncthreads();
        if (kt + 1 < nk) {
#pragma unroll
            for (int i = 0; i < 4; ++i) {
                int g = tid + i * 256, row = g >> 3, k8 = g & 7;
                av[i] = *reinterpret_cast<const uint4*>(A + (size_t)row * K + (kt + 1) * 64 + k8 * 8);
                bv[i] = *reinterpret_cast<const uint4*>(Bp + (size_t)row * K + (kt + 1) * 64 + k8 * 8);
            }
        }
#pragma unroll
        for (int kk = 0; kk < 2; ++kk) {
            bf16x8 af[4], bff[4];
#pragma unroll
            for (int mt = 0; mt < 4; ++mt) {
                int row = wm * 64 + mt * 16 + l16;
                int gs = (kk * 4 + lg) ^ (row & 7);
                af[mt] = *reinterpret_cast<const bf16x8*>(a_lds + row * 64 + gs * 8);
            }
#pragma unroll
            for (int nt = 0; nt < 4; ++nt) {
                int row = wn * 64 + nt * 16 + l16;
                int gs = (kk * 4 + lg) ^ (row & 7);
                bff[nt] = *reinterpret_cast<const bf16x8*>(b_lds + row * 64 + gs * 8);
            }
#pragma unroll
            for (int mt = 0; mt < 4; ++mt)
#pragma unroll
                for (int nt = 0; nt < 4; ++nt)
                    acc[mt][nt] = mfma16(af[mt], bff[nt], acc[mt][nt]);
        }
        __syncthreads();
    }
}

// q GEMM:  q[br] = xln[br] (36864x1024) @ WqT[br]^T  -> bf16 (36864x512)
__global__ __launch_bounds__(256, 2) void k_qgemm(const unsigned short* __restrict__ xln,
                                                  const unsigned short* __restrict__ wqt,
                                                  unsigned short* __restrict__ qb) {
    int bn = blockIdx.x, bm = blockIdx.y, br = blockIdx.z;
    const unsigned short* A = xln + (size_t)br * BT_ * DIM_ + (size_t)bm * 128 * DIM_;
    const unsigned short* Bp = wqt + (size_t)br * 512 * 1024 + (size_t)bn * 128 * 1024;
    unsigned short* C = qb + (size_t)br * BT_ * TXT_;
    __shared__ unsigned short a_lds[128 * 64];
    __shared__ unsigned short b_lds[128 * 64];
    f32x4 acc[4][4];
    gemm_loop(A, Bp, DIM_, a_lds, b_lds, threadIdx.x, acc);
    const int l = threadIdx.x & 63, w = threadIdx.x >> 6;
    const int l16 = l & 15, lg = l >> 4, wm = w & 1, wn = w >> 1;
#pragma unroll
    for (int mt = 0; mt < 4; ++mt)
#pragma unroll
        for (int nt = 0; nt < 4; ++nt)
#pragma unroll
            for (int r = 0; r < 4; ++r) {
                int row = bm * 128 + wm * 64 + mt * 16 + lg * 4 + r;
                int col = bn * 128 + wn * 64 + nt * 16 + l16;
                C[(size_t)row * TXT_ + col] = f2bf(acc[mt][nt][r]);
            }
}

// final GEMM: y = xse (36864x512) @ Wf^T (1024x512) -> fp32 scattered into out layout
__global__ __launch_bounds__(256, 2) void k_fgemm(const unsigned short* __restrict__ xse,
                                                  const unsigned short* __restrict__ wfb,
                                                  float* __restrict__ out) {
    int bn = blockIdx.x, bm = blockIdx.y;
    const unsigned short* A = xse + (size_t)bm * 128 * TXT_;
    const unsigned short* Bp = wfb + (size_t)bn * 128 * TXT_;
    __shared__ unsigned short a_lds[128 * 64];
    __shared__ unsigned short b_lds[128 * 64];
    f32x4 acc[4][4];
    gemm_loop(A, Bp, TXT_, a_lds, b_lds, threadIdx.x, acc);
    const int l = threadIdx.x & 63, w = threadIdx.x >> 6;
    const int l16 = l & 15, lg = l >> 4, wm = w & 1, wn = w >> 1;
#pragma unroll
    for (int mt = 0; mt < 4; ++mt)
#pragma unroll
        for (int r = 0; r < 4; ++r) {
            int rowg = bm * 128 + wm * 64 + mt * 16 + lg * 4 + r;
            int b = rowg / TOK_, tk = rowg - b * TOK_;
            float* dst = out + ((size_t)(tk + 1) * B_ + b) * DIM_;
#pragma unroll
            for (int nt = 0; nt < 4; ++nt) {
                int col = bn * 128 + wn * 64 + nt * 16 + l16;
                dst[col] = acc[mt][nt][r];
            }
        }
}

// ---------------- flash attention: per (qtile32, b, branch) ----------------
__global__ __launch_bounds__(512, 2) void k_attn(const unsigned short* __restrict__ qbuf,
                                                 const unsigned short* __restrict__ kvn,
                                                 const unsigned short* __restrict__ kvt,
                                                 unsigned short* __restrict__ ob) {
    const int qt = blockIdx.x, b = blockIdx.y, br = blockIdx.z;
    const int tid = threadIdx.x;
    const int w = tid >> 6, l = tid & 63, l16 = l & 15, lg = l >> 4;

    __shared__ unsigned short k_lds[64 * 512];   // 64 KB, XOR-swizzled granules
    __shared__ float s_lds[32][68];
    __shared__ unsigned short p_lds[32][64];     // XOR-swizzled granules
    __shared__ float m_s[32], l_s[32], f_s[32];

    if (tid < 32) { m_s[tid] = -1e30f; l_s[tid] = 0.f; }

    const int rt = w & 1, ct = w >> 1;           // score tile: rows rt*16.., cols ct*16..
    const int qrow = qt * 32 + rt * 16 + l16;
    const unsigned short* qsrc = qbuf + ((size_t)br * BT_ + (size_t)b * TOK_ + qrow) * TXT_;
    bf16x8 aq[16];
#pragma unroll
    for (int ks = 0; ks < 16; ++ks)
        aq[ks] = *reinterpret_cast<const bf16x8*>(qsrc + ks * 32 + lg * 8);

    const f32x4 fz = {0.f, 0.f, 0.f, 0.f};
    f32x4 oacc[2][4];
#pragma unroll
    for (int i = 0; i < 2; ++i)
#pragma unroll
        for (int j = 0; j < 4; ++j) oacc[i][j] = fz;

    const int ebase = w * 64;                    // PV e-slice per wave
    const unsigned short* kvbase = kvn + (size_t)b * NT_ * TXT_;
    const unsigned short* vtbase = kvt + (size_t)b * TXT_ * NTP_;

    for (int c = 0; c < 16; ++c) {
        const int n0 = c * 64;
        // stage K chunk (64 x 512 bf16) into swizzled LDS
#pragma unroll
        for (int i = 0; i < 8; ++i) {
            int g = tid + i * 512;
            int nl = g >> 6, e8 = g & 63;
            int n = n0 + nl;
            uint4 v = make_uint4(0, 0, 0, 0);
            if (n < NT_) v = *reinterpret_cast<const uint4*>(kvbase + (size_t)n * TXT_ + e8 * 8);
            int e8s = e8 ^ (nl & 7);
            *reinterpret_cast<uint4*>(&k_lds[nl * 512 + e8s * 8]) = v;
        }
        __syncthreads();
        // scores: each wave one 16x16 tile, K=512
        f32x4 sacc = fz;
        const int krow = ct * 16 + l16;
#pragma unroll
        for (int ks = 0; ks < 16; ++ks) {
            int gs = (ks * 4 + lg) ^ (krow & 7);
            bf16x8 bk = *reinterpret_cast<const bf16x8*>(&k_lds[krow * 512 + gs * 8]);
            sacc = mfma16(aq[ks], bk, sacc);
        }
#pragma unroll
        for (int r = 0; r < 4; ++r)
            s_lds[rt * 16 + lg * 4 + r][ct * 16 + l16] = sacc[r];
        __syncthreads();
        // online softmax: 16 threads per row
        {
            int row = tid >> 4;
            int c0 = (tid & 15) * 4;
            float v0[4]; float mx = -1e30f;
#pragma unroll
            for (int j = 0; j < 4; ++j) {
                int n = n0 + c0 + j;
                v0[j] = (n < NT_) ? s_lds[row][c0 + j] * SCALE_ : -1e30f;
                mx = fmaxf(mx, v0[j]);
            }
#pragma unroll
            for (int d = 1; d < 16; d <<= 1) mx = fmaxf(mx, __shfl_xor(mx, d));
            float mprev = m_s[row];               // in-wave read-before-write: safe
            float mnew = fmaxf(mprev, mx);
            float fac = __expf(mprev - mnew);
            float ssum = 0.f;
#pragma unroll
            for (int j = 0; j < 4; ++j) {
                float p = (n0 + c0 + j < NT_) ? __expf(v0[j] - mnew) : 0.f;
                ssum += p;
                int cc = c0 + j;
                int ccs = (cc & 7) | (((cc >> 3) ^ (row & 7)) << 3);
                p_lds[row][ccs] = f2bf(p);
            }
#pragma unroll
            for (int d = 1; d < 16; d <<= 1) ssum += __shfl_xor(ssum, d);
            if ((tid & 15) == 0) {
                m_s[row] = mnew;
                l_s[row] = l_s[row] * fac + ssum;
                f_s[row] = fac;
            }
        }
        __syncthreads();
        // PV: rescale accumulators, then P (LDS) x V (kvt global)
#pragma unroll
        for (int mt = 0; mt < 2; ++mt)
#pragma unroll
            for (int r = 0; r < 4; ++r) {
                float fac = f_s[mt * 16 + lg * 4 + r];
#pragma unroll
                for (int nt = 0; nt < 4; ++nt) oacc[mt][nt][r] *= fac;
            }
#pragma unroll
        for (int kk = 0; kk < 2; ++kk) {
            int g0 = (kk * 4 + lg) ^ (l16 & 7);
            bf16x8 ap0 = *reinterpret_cast<const bf16x8*>(&p_lds[l16][g0 * 8]);
            int row1 = 16 + l16;
            int g1x = (kk * 4 + lg) ^ (row1 & 7);
            bf16x8 ap1 = *reinterpret_cast<const bf16x8*>(&p_lds[row1][g1x * 8]);
#pragma unroll
            for (int nt = 0; nt < 4; ++nt) {
                int e = ebase + nt * 16 + l16;
                bf16x8 bv = *reinterpret_cast<const bf16x8*>(vtbase + (size_t)e * NTP_ + n0 + kk * 32 + lg * 8);
                oacc[0][nt] = mfma16(ap0, bv, oacc[0][nt]);
                oacc[1][nt] = mfma16(ap1, bv, oacc[1][nt]);
            }
        }
    }
    // epilogue: O / l  -> bf16
#pragma unroll
    for (int mt = 0; mt < 2; ++mt)
#pragma unroll
        for (int r = 0; r < 4; ++r) {
            int row = mt * 16 + lg * 4 + r;
            float inv = 1.f / l_s[row];
            int trow = qt * 32 + row;
            unsigned short* dst = ob + ((size_t)br * BT_ + (size_t)b * TOK_ + trow) * TXT_;
#pragma unroll
            for (int nt = 0; nt < 4; ++nt) {
                int e = ebase + nt * 16 + l16;
                dst[e] = f2bf(oacc[mt][nt][r] * inv);
            }
        }
}

// ---------------- channel mean (o1) / max (o2) per row ----------------
__global__ void k_avgmax(const unsigned short* __restrict__ o1, const unsigned short* __restrict__ o2,
                         float* __restrict__ avgb, float* __restrict__ maxb) {
    int row = blockIdx.x * 4 + (threadIdx.x >> 6);
    int l = threadIdx.x & 63;
    float f[8];
    unpack8(*reinterpret_cast<const uint4*>(o1 + (size_t)row * TXT_ + l * 8), f);
    float s = f[0] + f[1] + f[2] + f[3] + f[4] + f[5] + f[6] + f[7];
    unpack8(*reinterpret_cast<const uint4*>(o2 + (size_t)row * TXT_ + l * 8), f);
    float mx = f[0];
#pragma unroll
    for (int j = 1; j < 8; ++j) mx = fmaxf(mx, f[j]);
#pragma unroll
    for (int d = 1; d < 64; d <<= 1) { s += __shfl_xor(s, d); mx = fmaxf(mx, __shfl_xor(mx, d)); }
    if (l == 0) { avgb[row] = s * (1.f / TXT_); maxb[row] = mx; }
}

// ---------------- 3x3 depthwise conv on 24x24 + sigmoid gates ----------------
__global__ void k_gate(const float* __restrict__ avgb, const float* __restrict__ maxb,
                       const float* __restrict__ cdw, float* __restrict__ g1, float* __restrict__ g2) {
    int idx = blockIdx.x * 256 + threadIdx.x;     // < 36864
    int b = idx / TOK_, hw = idx - b * TOK_, h = hw / H_, ww = hw - h * H_;
    float a1 = 0.f, a2 = 0.f;
#pragma unroll
    for (int ky = 0; ky < 3; ++ky)
#pragma unroll
        for (int kx = 0; kx < 3; ++kx) {
            int hh = h + ky - 1, wx = ww + kx - 1;
            if (hh >= 0 && hh < H_ && wx >= 0 && wx < H_) {
                float wv = cdw[ky * 3 + kx];
                int s = b * TOK_ + hh * H_ + wx;
                a1 += wv * avgb[s];
                a2 += wv * maxb[s];
            }
        }
    g1[idx] = 1.f / (1.f + __expf(-a1));
    g2[idx] = 1.f / (1.f + __expf(-a2));
}

// ---------------- x_se = o1*g1 + o2*g2 -> bf16 ----------------
__global__ void k_xse(const unsigned short* __restrict__ o1, const unsigned short* __restrict__ o2,
                      const float* __restrict__ g1, const float* __restrict__ g2,
                      unsigned short* __restrict__ xse) {
    int idx8 = blockIdx.x * 256 + threadIdx.x;    // < 36864*64
    int bt = idx8 >> 6, e8 = idx8 & 63;
    float f1[8], f2[8];
    unpack8(*reinterpret_cast<const uint4*>(o1 + (size_t)bt * TXT_ + e8 * 8), f1);
    unpack8(*reinterpret_cast<const uint4*>(o2 + (size_t)bt * TXT_ + e8 * 8), f2);
    float gg1 = g1[bt], gg2 = g2[bt];
    unsigned r[4];
#pragma unroll
    for (int j = 0; j < 4; ++j) {
        unsigned lo = f2bf(f1[2 * j] * gg1 + f2[2 * j] * gg2);
        unsigned hi = f2bf(f1[2 * j + 1] * gg1 + f2[2 * j + 1] * gg2);
        r[j] = lo | (hi << 16);
    }
    uint4 o = make_uint4(r[0], r[1], r[2], r[3]);
    *reinterpret_cast<uint4*>(xse + (size_t)bt * TXT_ + e8 * 8) = o;
}

// ---------------- launcher ----------------
extern "C" void kernel_launch(void* const* d_in, const int* in_sizes, int n_in,
                              void* d_out, int out_size, void* d_ws, size_t ws_size,
                              hipStream_t stream) {
    (void)in_sizes; (void)n_in; (void)out_size; (void)ws_size;
    const float* x    = (const float*)d_in[0];
    const float* tf   = (const float*)d_in[1];
    const float* lq1g = (const float*)d_in[2];
    const float* lq1b = (const float*)d_in[3];
    const float* lq2g = (const float*)d_in[4];
    const float* lq2b = (const float*)d_in[5];
    const float* lkvg = (const float*)d_in[6];
    const float* lkvb = (const float*)d_in[7];
    const float* wq1  = (const float*)d_in[8];
    const float* wq2  = (const float*)d_in[9];
    const float* cdw  = (const float*)d_in[10];
    const float* wf   = (const float*)d_in[11];
    float* out = (float*)d_out;

    char* ws = (char*)d_ws;
    size_t off = 0;
    auto carve = [&](size_t bytes) { char* p = ws + off; off += (bytes + 255) & ~(size_t)255; return p; };
    unsigned short* kvn  = (unsigned short*)carve((size_t)B_ * NT_ * TXT_ * 2);        // 65.5 MB
    unsigned short* kvt  = (unsigned short*)carve((size_t)B_ * TXT_ * NTP_ * 2);       // 67.1 MB
    unsigned short* wqt  = (unsigned short*)carve((size_t)2 * 512 * 1024 * 2);         // 2 MB
    unsigned short* wfb  = (unsigned short*)carve((size_t)1024 * 512 * 2);             // 1 MB
    float* avgb = (float*)carve((size_t)BT_ * 4);
    float* maxb = (float*)carve((size_t)BT_ * 4);
    float* g1v  = (float*)carve((size_t)BT_ * 4);
    float* g2v  = (float*)carve((size_t)BT_ * 4);
    unsigned short* xln  = (unsigned short*)carve((size_t)2 * BT_ * DIM_ * 2);         // 151 MB (ob aliases)
    unsigned short* qbuf = (unsigned short*)carve((size_t)2 * BT_ * TXT_ * 2);         // 75.5 MB (xse aliases)
    unsigned short* ob   = xln;    // safe: xln dead after k_qgemm
    unsigned short* xse  = qbuf;   // safe: qbuf dead after k_attn

    // row 0 of output = x_cls
    hipMemcpyAsync(out, x, (size_t)B_ * DIM_ * sizeof(float), hipMemcpyDeviceToDevice, stream);

    k_prep_wq<<<256, 256, 0, stream>>>(wq1, wq2, wqt);
    k_f2bf<<<512, 256, 0, stream>>>(wf, wfb, 131072);
    k_kvln<<<B_ * NT_, 128, 0, stream>>>(tf, lkvg, lkvb, kvn);
    k_kvt<<<8192, 256, 0, stream>>>(kvn, kvt);
    k_xln<<<BT_, 256, 0, stream>>>(x, lq1g, lq1b, lq2g, lq2b, xln);
    k_qgemm<<<dim3(4, 288, 2), 256, 0, stream>>>(xln, wqt, qbuf);
    k_attn<<<dim3(18, 64, 2), 512, 0, stream>>>(qbuf, kvn, kvt, ob);
    k_avgmax<<<9216, 256, 0, stream>>>(ob, ob + (size_t)BT_ * TXT_, avgb, maxb);
    k_gate<<<144, 256, 0, stream>>>(avgb, maxb, cdw, g1v, g2v);
    k_xse<<<9216, 256, 0, stream>>>(ob, ob + (size_t)BT_ * TXT_, g1v, g2v, xse);
    k_fgemm<<<dim3(8, 288, 1), 256, 0, stream>>>(xse, wfb, out);
}

// Round 2
// 972.647 us; speedup vs baseline: 2.0556x; 2.0556x over previous
//
#include <hip/hip_runtime.h>

// ---------------- problem constants ----------------
#define B_    64
#define TOK_  576
#define DIM_  1024
#define TXT_  512
#define NT_   1000
#define NTQ_  1024                 // kvn padded rows (zero-filled 1000..1023)
#define NTP_  1024                 // kvt padded cols
#define H_    24
#define BT_   (B_ * TOK_)          // 36864 rows
static constexpr float SCALE_ = 0.0441941738241592f;   // 512^-0.5

typedef __bf16 bf16x8 __attribute__((ext_vector_type(8)));
typedef float  f32x4  __attribute__((ext_vector_type(4)));

__device__ __forceinline__ unsigned short f2bf(float f) {
    unsigned u = __float_as_uint(f);
    u += 0x7fffu + ((u >> 16) & 1u);
    return (unsigned short)(u >> 16);
}
__device__ __forceinline__ float bf2f(unsigned short h) {
    return __uint_as_float(((unsigned)h) << 16);
}
__device__ __forceinline__ f32x4 mfma16(bf16x8 a, bf16x8 b, f32x4 c) {
    return __builtin_amdgcn_mfma_f32_16x16x32_bf16(a, b, c, 0, 0, 0);
}
__device__ __forceinline__ void unpack8(uint4 v, float* f) {
    unsigned a0 = v.x, a1 = v.y, a2 = v.z, a3 = v.w;
    f[0] = bf2f((unsigned short)(a0 & 0xffff)); f[1] = bf2f((unsigned short)(a0 >> 16));
    f[2] = bf2f((unsigned short)(a1 & 0xffff)); f[3] = bf2f((unsigned short)(a1 >> 16));
    f[4] = bf2f((unsigned short)(a2 & 0xffff)); f[5] = bf2f((unsigned short)(a2 >> 16));
    f[6] = bf2f((unsigned short)(a3 & 0xffff)); f[7] = bf2f((unsigned short)(a3 >> 16));
}

// async global->LDS, 16B per lane; lds base must be wave-uniform, lanes land at base + lane*16
typedef const __attribute__((address_space(1))) unsigned int* as1_u32p;
typedef __attribute__((address_space(3))) unsigned int* as3_u32p;
__device__ __forceinline__ void gll16(const void* g, void* l) {
    __builtin_amdgcn_global_load_lds((as1_u32p)g, (as3_u32p)l, 16, 0, 0);
}

// ---------------- weight prep ----------------
// Wq (1024x512 f32), rows pre-scaled by LN gamma -> WqT bf16 [branch][512][1024]
__global__ void k_prep_wq(const float* __restrict__ wq1, const float* __restrict__ wq2,
                          const float* __restrict__ g1, const float* __restrict__ g2,
                          unsigned short* __restrict__ wqt) {
    __shared__ float tile[64][68];
    int bx = blockIdx.x, t = threadIdx.x;
    int br = bx >> 7, kt = (bx >> 3) & 15, nt = bx & 7;
    const float* wq = br ? wq2 : wq1;
    const float* gg = br ? g2 : g1;
#pragma unroll
    for (int i = 0; i < 4; ++i) {
        int idx4 = t + i * 256;
        int kl = idx4 >> 4, n4 = (idx4 & 15) * 4;
        float gv = gg[kt * 64 + kl];
        float4 v = *reinterpret_cast<const float4*>(wq + (size_t)(kt * 64 + kl) * 512 + nt * 64 + n4);
        tile[kl][n4 + 0] = v.x * gv; tile[kl][n4 + 1] = v.y * gv;
        tile[kl][n4 + 2] = v.z * gv; tile[kl][n4 + 3] = v.w * gv;
    }
    __syncthreads();
#pragma unroll
    for (int i = 0; i < 4; ++i) {
        int idx4 = t + i * 256;
        int nl = idx4 >> 4, k4 = (idx4 & 15) * 4;
        ushort4 o = make_ushort4(f2bf(tile[k4 + 0][nl]), f2bf(tile[k4 + 1][nl]),
                                 f2bf(tile[k4 + 2][nl]), f2bf(tile[k4 + 3][nl]));
        *reinterpret_cast<ushort4*>(wqt + (size_t)br * 512 * 1024 + (size_t)(nt * 64 + nl) * 1024 + kt * 64 + k4) = o;
    }
}

// qbias[br][e] = sum_d beta[d] * Wq[d][e]
__global__ void k_qbias(const float* __restrict__ wq1, const float* __restrict__ wq2,
                        const float* __restrict__ b1, const float* __restrict__ b2,
                        float* __restrict__ qbias) {
    int br = blockIdx.x >> 3;
    int e = (blockIdx.x & 7) * 64 + threadIdx.x;
    const float* wq = br ? wq2 : wq1;
    const float* bb = br ? b2 : b1;
    float s = 0.f;
    for (int d = 0; d < DIM_; ++d) s += bb[d] * wq[(size_t)d * 512 + e];
    qbias[br * 512 + e] = s;
}

__global__ void k_f2bf(const float* __restrict__ src, unsigned short* __restrict__ dst, int n4) {
    int i = blockIdx.x * blockDim.x + threadIdx.x;
    if (i < n4) {
        float4 v = *reinterpret_cast<const float4*>(src + (size_t)i * 4);
        ushort4 o = make_ushort4(f2bf(v.x), f2bf(v.y), f2bf(v.z), f2bf(v.w));
        *reinterpret_cast<ushort4*>(dst + (size_t)i * 4) = o;
    }
}

// ---------------- kv layernorm:  text_fea (NT,B,TXT) -> kvn bf16 [b][n_pad1024][e] ----------------
__global__ void k_kvln(const float* __restrict__ tf, const float* __restrict__ g,
                       const float* __restrict__ bta, unsigned short* __restrict__ kvn) {
    int row = blockIdx.x;                 // b*1024 + n
    int b = row >> 10, n = row & 1023;
    int t = threadIdx.x;                  // 128 threads, 4 elems each
    unsigned short* dst = kvn + ((size_t)b * NTQ_ + n) * TXT_;
    if (n >= NT_) {                       // zero-pad rows
        *reinterpret_cast<ushort4*>(dst + t * 4) = make_ushort4(0, 0, 0, 0);
        return;
    }
    const float* src = tf + ((size_t)n * B_ + b) * TXT_;
    float4 v = *reinterpret_cast<const float4*>(src + t * 4);
    float s = v.x + v.y + v.z + v.w;
    float ss = v.x * v.x + v.y * v.y + v.z * v.z + v.w * v.w;
#pragma unroll
    for (int d = 1; d < 64; d <<= 1) { s += __shfl_xor(s, d); ss += __shfl_xor(ss, d); }
    __shared__ float red[4];
    if ((t & 63) == 0) { red[(t >> 6) * 2] = s; red[(t >> 6) * 2 + 1] = ss; }
    __syncthreads();
    s = red[0] + red[2]; ss = red[1] + red[3];
    float m = s * (1.f / TXT_);
    float rs = rsqrtf(ss * (1.f / TXT_) - m * m + 1e-5f);
    int d0 = t * 4;
    ushort4 o = make_ushort4(f2bf((v.x - m) * rs * g[d0 + 0] + bta[d0 + 0]),
                             f2bf((v.y - m) * rs * g[d0 + 1] + bta[d0 + 1]),
                             f2bf((v.z - m) * rs * g[d0 + 2] + bta[d0 + 2]),
                             f2bf((v.w - m) * rs * g[d0 + 3] + bta[d0 + 3]));
    *reinterpret_cast<ushort4*>(dst + d0) = o;
}

// ---------------- kv transpose:  kvn [b][n][e] -> kvt [b][e][n_pad1024] ----------------
__global__ void k_kvt(const unsigned short* __restrict__ kvn, unsigned short* __restrict__ kvt) {
    __shared__ unsigned short tile[64][68];
    int bx = blockIdx.x;
    int b = bx >> 7, rem = bx & 127, et = rem >> 4, nt = rem & 15;
    int t = threadIdx.x;
#pragma unroll
    for (int i = 0; i < 4; ++i) {
        int idx4 = t + i * 256;
        int nl = idx4 >> 4, e4 = (idx4 & 15) * 4;
        int ng = nt * 64 + nl;
        ushort4 v = make_ushort4(0, 0, 0, 0);
        if (ng < NT_) v = *reinterpret_cast<const ushort4*>(kvn + ((size_t)b * NTQ_ + ng) * TXT_ + et * 64 + e4);
        tile[nl][e4 + 0] = v.x; tile[nl][e4 + 1] = v.y; tile[nl][e4 + 2] = v.z; tile[nl][e4 + 3] = v.w;
    }
    __syncthreads();
#pragma unroll
    for (int i = 0; i < 4; ++i) {
        int idx4 = t + i * 256;
        int el = idx4 >> 4, n4 = (idx4 & 15) * 4;
        ushort4 o = make_ushort4(tile[n4 + 0][el], tile[n4 + 1][el], tile[n4 + 2][el], tile[n4 + 3][el]);
        *reinterpret_cast<ushort4*>(kvt + ((size_t)b * TXT_ + et * 64 + el) * NTP_ + nt * 64 + n4) = o;
    }
}

// ---------------- x layernorm (normalized only; gamma/beta folded into Wq) ----------------
__global__ void k_xln(const float* __restrict__ x, unsigned short* __restrict__ xn) {
    int bt = blockIdx.x;                   // b*TOK + t
    int b = bt / TOK_, tk = bt - b * TOK_;
    const float* src = x + ((size_t)(tk + 1) * B_ + b) * DIM_;
    int t = threadIdx.x;                   // 256 threads, 4 floats each
    float4 v = *reinterpret_cast<const float4*>(src + t * 4);
    float s = v.x + v.y + v.z + v.w;
    float ss = v.x * v.x + v.y * v.y + v.z * v.z + v.w * v.w;
#pragma unroll
    for (int d = 1; d < 64; d <<= 1) { s += __shfl_xor(s, d); ss += __shfl_xor(ss, d); }
    __shared__ float red[8];
    if ((t & 63) == 0) { red[t >> 6] = s; red[4 + (t >> 6)] = ss; }
    __syncthreads();
    s = red[0] + red[1] + red[2] + red[3];
    ss = red[4] + red[5] + red[6] + red[7];
    float m = s * (1.f / DIM_);
    float rs = rsqrtf(ss * (1.f / DIM_) - m * m + 1e-5f);
    int d0 = t * 4;
    ushort4 o = make_ushort4(f2bf((v.x - m) * rs), f2bf((v.y - m) * rs),
                             f2bf((v.z - m) * rs), f2bf((v.w - m) * rs));
    *reinterpret_cast<ushort4*>(xn + (size_t)bt * DIM_ + d0) = o;
}

// ---------------- shared 128x128xK bf16 GEMM mainloop, global_load_lds staging ----------------
// A:[M][K], B:[N][K], both k-contiguous, rows 16B aligned. m97 structure.
__device__ __forceinline__ void gemm_loop_gll(const unsigned short* __restrict__ A,
                                              const unsigned short* __restrict__ Bp,
                                              int K, unsigned short* a_lds, unsigned short* b_lds,
                                              int tid, f32x4 acc[4][4]) {
    const int l = tid & 63, w = tid >> 6;
    const int l16 = l & 15, lg = l >> 4;
    const int wm = w & 1, wn = w >> 1;
    const f32x4 fz = {0.f, 0.f, 0.f, 0.f};
#pragma unroll
    for (int mt = 0; mt < 4; ++mt)
#pragma unroll
        for (int nt = 0; nt < 4; ++nt) acc[mt][nt] = fz;
    const int lrow = l >> 3;               // 0..7
    const int k8g = (l & 7) ^ lrow;        // pre-swizzled source granule
    const int nk = K >> 6;
    for (int kt = 0; kt < nk; ++kt) {
#pragma unroll
        for (int i = 0; i < 4; ++i) {
            int row = i * 32 + w * 8 + lrow;
            gll16(A + (size_t)row * K + kt * 64 + k8g * 8, &a_lds[(i * 256 + w * 64) * 8]);
        }
#pragma unroll
        for (int i = 0; i < 4; ++i) {
            int row = i * 32 + w * 8 + lrow;
            gll16(Bp + (size_t)row * K + kt * 64 + k8g * 8, &b_lds[(i * 256 + w * 64) * 8]);
        }
        __syncthreads();                   // drains vmcnt -> LDS writes visible
#pragma unroll
        for (int kk = 0; kk < 2; ++kk) {
            bf16x8 af[4], bff[4];
#pragma unroll
            for (int mt = 0; mt < 4; ++mt) {
                int row = wm * 64 + mt * 16 + l16;
                int gs = (kk * 4 + lg) ^ (row & 7);
                af[mt] = *reinterpret_cast<const bf16x8*>(a_lds + row * 64 + gs * 8);
            }
#pragma unroll
            for (int nt = 0; nt < 4; ++nt) {
                int row = wn * 64 + nt * 16 + l16;
                int gs = (kk * 4 + lg) ^ (row & 7);
                bff[nt] = *reinterpret_cast<const bf16x8*>(b_lds + row * 64 + gs * 8);
            }
#pragma unroll
            for (int mt = 0; mt < 4; ++mt)
#pragma unroll
                for (int nt = 0; nt < 4; ++nt)
                    acc[mt][nt] = mfma16(af[mt], bff[nt], acc[mt][nt]);
        }
        __syncthreads();
    }
}

// q GEMM:  q[br] = xn (36864x1024) @ (diag(g)Wq[br])^T + bias  -> bf16 (36864x512)
__global__ __launch_bounds__(256, 4) void k_qgemm(const unsigned short* __restrict__ xn,
                                                  const unsigned short* __restrict__ wqt,
                                                  const float* __restrict__ qbias,
                                                  unsigned short* __restrict__ qb) {
    int bid = blockIdx.x;                        // 2304 = 4bn x 288bm x 2br
    int vb = (bid & 7) * 288 + (bid >> 3);       // XCD-contiguous
    int bn = vb & 3;
    int t = vb >> 2;
    int br = (t >= 288) ? 1 : 0;
    int bm = t - br * 288;
    const unsigned short* A = xn + (size_t)bm * 128 * DIM_;
    const unsigned short* Bp = wqt + (size_t)br * 512 * 1024 + (size_t)bn * 128 * 1024;
    unsigned short* C = qb + (size_t)br * BT_ * TXT_;
    const float* bias = qbias + br * 512;
    __shared__ unsigned short a_lds[128 * 64];
    __shared__ unsigned short b_lds[128 * 64];
    f32x4 acc[4][4];
    gemm_loop_gll(A, Bp, DIM_, a_lds, b_lds, threadIdx.x, acc);
    const int l = threadIdx.x & 63, w = threadIdx.x >> 6;
    const int l16 = l & 15, lg = l >> 4, wm = w & 1, wn = w >> 1;
#pragma unroll
    for (int mt = 0; mt < 4; ++mt)
#pragma unroll
        for (int nt = 0; nt < 4; ++nt) {
            int col = bn * 128 + wn * 64 + nt * 16 + l16;
            float bv = bias[col];
#pragma unroll
            for (int r = 0; r < 4; ++r) {
                int row = bm * 128 + wm * 64 + mt * 16 + lg * 4 + r;
                C[(size_t)row * TXT_ + col] = f2bf(acc[mt][nt][r] + bv);
            }
        }
}

// final GEMM: y = xse (36864x512) @ Wf^T (1024x512) -> fp32 scattered into out layout
__global__ __launch_bounds__(256, 4) void k_fgemm(const unsigned short* __restrict__ xse,
                                                  const unsigned short* __restrict__ wfb,
                                                  float* __restrict__ out) {
    int bid = blockIdx.x;                        // 2304 = 8bn x 288bm
    int vb = (bid & 7) * 288 + (bid >> 3);
    int bn = vb & 7, bm = vb >> 3;
    const unsigned short* A = xse + (size_t)bm * 128 * TXT_;
    const unsigned short* Bp = wfb + (size_t)bn * 128 * TXT_;
    __shared__ unsigned short a_lds[128 * 64];
    __shared__ unsigned short b_lds[128 * 64];
    f32x4 acc[4][4];
    gemm_loop_gll(A, Bp, TXT_, a_lds, b_lds, threadIdx.x, acc);
    const int l = threadIdx.x & 63, w = threadIdx.x >> 6;
    const int l16 = l & 15, lg = l >> 4, wm = w & 1, wn = w >> 1;
#pragma unroll
    for (int mt = 0; mt < 4; ++mt)
#pragma unroll
        for (int r = 0; r < 4; ++r) {
            int rowg = bm * 128 + wm * 64 + mt * 16 + lg * 4 + r;
            int b = rowg / TOK_, tk = rowg - b * TOK_;
            float* dst = out + ((size_t)(tk + 1) * B_ + b) * DIM_;
#pragma unroll
            for (int nt = 0; nt < 4; ++nt) {
                int col = bn * 128 + wn * 64 + nt * 16 + l16;
                dst[col] = acc[mt][nt][r];
            }
        }
}

// ---------------- attention v2: no-max softmax, K direct from global, fused avg/max ----------------
// block = (qt: 32 q-rows, b, br), 4 waves. wave w: score cols w*16 (both 16-row halves),
// PV e-slice w*128. Q staged once in LDS (swizzled). 2 barriers/chunk.
__global__ __launch_bounds__(256, 3) void k_attn(const unsigned short* __restrict__ qbuf,
                                                 const unsigned short* __restrict__ kvn,
                                                 const unsigned short* __restrict__ kvt,
                                                 unsigned short* __restrict__ ob,
                                                 float* __restrict__ avgb,
                                                 float* __restrict__ maxb) {
    int bid = blockIdx.x;                        // 2304 = 18qt x 64b x 2br
    int vb = (bid & 7) * 288 + (bid >> 3);       // XCD-contiguous (qt fastest)
    int qt = vb % 18;
    int rem = vb / 18;
    int b = rem & 63;
    int br = rem >> 6;

    const int tid = threadIdx.x;
    const int w = tid >> 6, l = tid & 63, l16 = l & 15, lg = l >> 4;

    __shared__ unsigned short q_lds[32 * 512];   // 32 KB, XOR-swizzled granules
    __shared__ unsigned short p_lds[32 * 64];    // 4 KB,  XOR-swizzled granules
    __shared__ float f_lds[4][32];

    // stage Q (32x512) via global_load_lds; each wave-instr covers one row (64 granules)
    const unsigned short* qsrc = qbuf + ((size_t)br * BT_ + (size_t)b * TOK_ + qt * 32) * TXT_;
#pragma unroll
    for (int i = 0; i < 8; ++i) {
        int row = w + i * 4;
        gll16(qsrc + (size_t)row * TXT_ + ((l ^ (row & 7)) * 8), &q_lds[row * 512]);
    }
    __syncthreads();

    const f32x4 fz = {0.f, 0.f, 0.f, 0.f};
    f32x4 oacc[2][8];
#pragma unroll
    for (int i = 0; i < 2; ++i)
#pragma unroll
        for (int j = 0; j < 8; ++j) oacc[i][j] = fz;
    float denomp[2][4] = {{0.f, 0.f, 0.f, 0.f}, {0.f, 0.f, 0.f, 0.f}};

    const unsigned short* kbase = kvn + (size_t)b * NTQ_ * TXT_;
    const unsigned short* vtbase = kvt + (size_t)b * TXT_ * NTP_;

    for (int c = 0; c < 16; ++c) {
        const int n0 = c * 64;
        // ---- scores: 2 tiles (rows 0-15 / 16-31), cols w*16, K=512, direct-global K
        f32x4 s0 = fz, s1 = fz, s0b = fz, s1b = fz;
        const unsigned short* kptr = kbase + (size_t)(n0 + w * 16 + l16) * TXT_ + lg * 8;
#pragma unroll
        for (int ks = 0; ks < 16; ++ks) {
            bf16x8 bk = *reinterpret_cast<const bf16x8*>(kptr + ks * 32);
            int gs = ((ks * 4 + lg) ^ (l16 & 7)) * 8;
            bf16x8 a0 = *reinterpret_cast<const bf16x8*>(&q_lds[l16 * 512 + gs]);
            bf16x8 a1 = *reinterpret_cast<const bf16x8*>(&q_lds[(16 + l16) * 512 + gs]);
            if (ks & 1) { s0b = mfma16(a0, bk, s0b); s1b = mfma16(a1, bk, s1b); }
            else        { s0  = mfma16(a0, bk, s0);  s1  = mfma16(a1, bk, s1); }
        }
        s0 += s0b; s1 += s1b;
        // ---- exp (no max), denom accumulate, P -> LDS bf16
        const bool valid = (n0 + w * 16 + l16) < NT_;
        const int gcol = w * 2 + (l16 >> 3);
#pragma unroll
        for (int r = 0; r < 4; ++r) {
            float p0 = valid ? __expf(s0[r] * SCALE_) : 0.f;
            float p1 = valid ? __expf(s1[r] * SCALE_) : 0.f;
            denomp[0][r] += p0; denomp[1][r] += p1;
            int row0 = 4 * lg + r, row1 = 16 + 4 * lg + r;
            p_lds[row0 * 64 + ((gcol ^ (row0 & 7)) * 8) + (l16 & 7)] = f2bf(p0);
            p_lds[row1 * 64 + ((gcol ^ (row1 & 7)) * 8) + (l16 & 7)] = f2bf(p1);
        }
        // ---- prefetch V (kk=0) before barrier: independent of p_lds
        bf16x8 bv0[8];
#pragma unroll
        for (int nt = 0; nt < 8; ++nt) {
            int e = w * 128 + nt * 16 + l16;
            bv0[nt] = *reinterpret_cast<const bf16x8*>(vtbase + (size_t)e * NTP_ + n0 + lg * 8);
        }
        __syncthreads();
        // ---- PV: kk=0 with prefetched V, then kk=1
        {
            int r1 = 16 + l16;
            bf16x8 ap00 = *reinterpret_cast<const bf16x8*>(&p_lds[l16 * 64 + (lg ^ (l16 & 7)) * 8]);
            bf16x8 ap10 = *reinterpret_cast<const bf16x8*>(&p_lds[r1 * 64 + (lg ^ (r1 & 7)) * 8]);
            __builtin_amdgcn_s_setprio(1);
#pragma unroll
            for (int nt = 0; nt < 8; ++nt) {
                oacc[0][nt] = mfma16(ap00, bv0[nt], oacc[0][nt]);
                oacc[1][nt] = mfma16(ap10, bv0[nt], oacc[1][nt]);
            }
            __builtin_amdgcn_s_setprio(0);
            bf16x8 ap01 = *reinterpret_cast<const bf16x8*>(&p_lds[l16 * 64 + ((4 + lg) ^ (l16 & 7)) * 8]);
            bf16x8 ap11 = *reinterpret_cast<const bf16x8*>(&p_lds[r1 * 64 + ((4 + lg) ^ (r1 & 7)) * 8]);
#pragma unroll
            for (int nt = 0; nt < 8; ++nt) {
                int e = w * 128 + nt * 16 + l16;
                bf16x8 bv = *reinterpret_cast<const bf16x8*>(vtbase + (size_t)e * NTP_ + n0 + 32 + lg * 8);
                oacc[0][nt] = mfma16(ap01, bv, oacc[0][nt]);
                oacc[1][nt] = mfma16(ap11, bv, oacc[1][nt]);
            }
        }
        __syncthreads();
    }

    // ---- denominator: reduce over l16 lanes, then across the 4 waves via LDS
#pragma unroll
    for (int i = 0; i < 2; ++i)
#pragma unroll
        for (int r = 0; r < 4; ++r) {
            float v = denomp[i][r];
#pragma unroll
            for (int d = 1; d < 16; d <<= 1) v += __shfl_xor(v, d);
            denomp[i][r] = v;
        }
    if (l16 == 0) {
#pragma unroll
        for (int i = 0; i < 2; ++i)
#pragma unroll
            for (int r = 0; r < 4; ++r)
                f_lds[w][i * 16 + 4 * lg + r] = denomp[i][r];
    }
    __syncthreads();
    float inv[2][4];
#pragma unroll
    for (int i = 0; i < 2; ++i)
#pragma unroll
        for (int r = 0; r < 4; ++r) {
            int row = i * 16 + 4 * lg + r;
            inv[i][r] = 1.f / (f_lds[0][row] + f_lds[1][row] + f_lds[2][row] + f_lds[3][row]);
        }
    __syncthreads();                               // f_lds reused below

    // ---- epilogue: O -> bf16, fused per-row sum (br0) / max (br1) over e
    const bool isavg = (br == 0);
    float stat[2][4];
#pragma unroll
    for (int mt = 0; mt < 2; ++mt)
#pragma unroll
        for (int r = 0; r < 4; ++r) {
            float iv = inv[mt][r];
            float s = isavg ? 0.f : -1e30f;
            int rowg = qt * 32 + mt * 16 + 4 * lg + r;
            unsigned short* dst = ob + ((size_t)br * BT_ + (size_t)b * TOK_ + rowg) * TXT_;
#pragma unroll
            for (int nt = 0; nt < 8; ++nt) {
                float o = oacc[mt][nt][r] * iv;
                dst[w * 128 + nt * 16 + l16] = f2bf(o);
                s = isavg ? (s + o) : fmaxf(s, o);
            }
            stat[mt][r] = s;
        }
#pragma unroll
    for (int mt = 0; mt < 2; ++mt)
#pragma unroll
        for (int r = 0; r < 4; ++r) {
            float v = stat[mt][r];
#pragma unroll
            for (int d = 1; d < 16; d <<= 1) {
                float o = __shfl_xor(v, d);
                v = isavg ? (v + o) : fmaxf(v, o);
            }
            stat[mt][r] = v;
        }
    if (l16 == 0) {
#pragma unroll
        for (int mt = 0; mt < 2; ++mt)
#pragma unroll
            for (int r = 0; r < 4; ++r)
                f_lds[w][mt * 16 + 4 * lg + r] = stat[mt][r];
    }
    __syncthreads();
    if (tid < 32) {
        float v0 = f_lds[0][tid], v1 = f_lds[1][tid], v2 = f_lds[2][tid], v3 = f_lds[3][tid];
        int rowg = b * TOK_ + qt * 32 + tid;
        if (isavg) avgb[rowg] = (v0 + v1 + v2 + v3) * (1.f / TXT_);
        else       maxb[rowg] = fmaxf(fmaxf(v0, v1), fmaxf(v2, v3));
    }
}

// ---------------- 3x3 depthwise conv on 24x24 + sigmoid gates ----------------
__global__ void k_gate(const float* __restrict__ avgb, const float* __restrict__ maxb,
                       const float* __restrict__ cdw, float* __restrict__ g1, float* __restrict__ g2) {
    int idx = blockIdx.x * 256 + threadIdx.x;     // < 36864
    int b = idx / TOK_, hw = idx - b * TOK_, h = hw / H_, ww = hw - h * H_;
    float a1 = 0.f, a2 = 0.f;
#pragma unroll
    for (int ky = 0; ky < 3; ++ky)
#pragma unroll
        for (int kx = 0; kx < 3; ++kx) {
            int hh = h + ky - 1, wx = ww + kx - 1;
            if (hh >= 0 && hh < H_ && wx >= 0 && wx < H_) {
                float wv = cdw[ky * 3 + kx];
                int s = b * TOK_ + hh * H_ + wx;
                a1 += wv * avgb[s];
                a2 += wv * maxb[s];
            }
        }
    g1[idx] = 1.f / (1.f + __expf(-a1));
    g2[idx] = 1.f / (1.f + __expf(-a2));
}

// ---------------- x_se = o1*g1 + o2*g2 -> bf16 ----------------
__global__ void k_xse(const unsigned short* __restrict__ o1, const unsigned short* __restrict__ o2,
                      const float* __restrict__ g1, const float* __restrict__ g2,
                      unsigned short* __restrict__ xse) {
    int idx8 = blockIdx.x * 256 + threadIdx.x;    // < 36864*64
    int bt = idx8 >> 6, e8 = idx8 & 63;
    float f1[8], f2[8];
    unpack8(*reinterpret_cast<const uint4*>(o1 + (size_t)bt * TXT_ + e8 * 8), f1);
    unpack8(*reinterpret_cast<const uint4*>(o2 + (size_t)bt * TXT_ + e8 * 8), f2);
    float gg1 = g1[bt], gg2 = g2[bt];
    unsigned r[4];
#pragma unroll
    for (int j = 0; j < 4; ++j) {
        unsigned lo = f2bf(f1[2 * j] * gg1 + f2[2 * j] * gg2);
        unsigned hi = f2bf(f1[2 * j + 1] * gg1 + f2[2 * j + 1] * gg2);
        r[j] = lo | (hi << 16);
    }
    uint4 o = make_uint4(r[0], r[1], r[2], r[3]);
    *reinterpret_cast<uint4*>(xse + (size_t)bt * TXT_ + e8 * 8) = o;
}

// ---------------- launcher ----------------
extern "C" void kernel_launch(void* const* d_in, const int* in_sizes, int n_in,
                              void* d_out, int out_size, void* d_ws, size_t ws_size,
                              hipStream_t stream) {
    (void)in_sizes; (void)n_in; (void)out_size; (void)ws_size;
    const float* x    = (const float*)d_in[0];
    const float* tf   = (const float*)d_in[1];
    const float* lq1g = (const float*)d_in[2];
    const float* lq1b = (const float*)d_in[3];
    const float* lq2g = (const float*)d_in[4];
    const float* lq2b = (const float*)d_in[5];
    const float* lkvg = (const float*)d_in[6];
    const float* lkvb = (const float*)d_in[7];
    const float* wq1  = (const float*)d_in[8];
    const float* wq2  = (const float*)d_in[9];
    const float* cdw  = (const float*)d_in[10];
    const float* wf   = (const float*)d_in[11];
    float* out = (float*)d_out;

    char* ws = (char*)d_ws;
    size_t off = 0;
    auto carve = [&](size_t bytes) { char* p = ws + off; off += (bytes + 255) & ~(size_t)255; return p; };
    unsigned short* kvn  = (unsigned short*)carve((size_t)B_ * NTQ_ * TXT_ * 2);       // 67.1 MB
    unsigned short* kvt  = (unsigned short*)carve((size_t)B_ * TXT_ * NTP_ * 2);       // 67.1 MB
    unsigned short* wqt  = (unsigned short*)carve((size_t)2 * 512 * 1024 * 2);         // 2 MB
    unsigned short* wfb  = (unsigned short*)carve((size_t)1024 * 512 * 2);             // 1 MB
    float* qbias = (float*)carve((size_t)2 * 512 * 4);
    float* avgb = (float*)carve((size_t)BT_ * 4);
    float* maxb = (float*)carve((size_t)BT_ * 4);
    float* g1v  = (float*)carve((size_t)BT_ * 4);
    float* g2v  = (float*)carve((size_t)BT_ * 4);
    unsigned short* xn   = (unsigned short*)carve((size_t)BT_ * DIM_ * 2);             // 75.5 MB
    unsigned short* qbuf = (unsigned short*)carve((size_t)2 * BT_ * TXT_ * 2);         // 75.5 MB
    unsigned short* ob   = xn;     // safe: xn dead after k_qgemm
    unsigned short* xse  = qbuf;   // safe: qbuf dead after k_attn

    // row 0 of output = x_cls
    hipMemcpyAsync(out, x, (size_t)B_ * DIM_ * sizeof(float), hipMemcpyDeviceToDevice, stream);

    k_prep_wq<<<256, 256, 0, stream>>>(wq1, wq2, lq1g, lq2g, wqt);
    k_qbias<<<16, 64, 0, stream>>>(wq1, wq2, lq1b, lq2b, qbias);
    k_f2bf<<<512, 256, 0, stream>>>(wf, wfb, 131072);
    k_kvln<<<B_ * NTQ_, 128, 0, stream>>>(tf, lkvg, lkvb, kvn);
    k_kvt<<<8192, 256, 0, stream>>>(kvn, kvt);
    k_xln<<<BT_, 256, 0, stream>>>(x, xn);
    k_qgemm<<<2304, 256, 0, stream>>>(xn, wqt, qbias, qbuf);
    k_attn<<<2304, 256, 0, stream>>>(qbuf, kvn, kvt, ob, avgb, maxb);
    k_gate<<<144, 256, 0, stream>>>(avgb, maxb, cdw, g1v, g2v);
    k_xse<<<9216, 256, 0, stream>>>(ob, ob + (size_t)BT_ * TXT_, g1v, g2v, xse);
    k_fgemm<<<2304, 256, 0, stream>>>(xse, wfb, out);
}

// Round 3
// 608.312 us; speedup vs baseline: 3.2868x; 1.5989x over previous
//
#include <hip/hip_runtime.h>

// ---------------- problem constants ----------------
#define B_    64
#define TOK_  576
#define DIM_  1024
#define TXT_  512
#define NT_   1000
#define NTQ_  1024                 // kvn padded rows (zero-filled 1000..1023)
#define NTP_  1024                 // kvt padded cols / P padded cols
#define H_    24
#define BT_   (B_ * TOK_)          // 36864 rows
static constexpr float SCALE_ = 0.0441941738241592f;   // 512^-0.5

typedef __bf16 bf16x8 __attribute__((ext_vector_type(8)));
typedef float  f32x4  __attribute__((ext_vector_type(4)));

__device__ __forceinline__ unsigned short f2bf(float f) {
    unsigned u = __float_as_uint(f);
    u += 0x7fffu + ((u >> 16) & 1u);
    return (unsigned short)(u >> 16);
}
__device__ __forceinline__ float bf2f(unsigned short h) {
    return __uint_as_float(((unsigned)h) << 16);
}
__device__ __forceinline__ f32x4 mfma16(bf16x8 a, bf16x8 b, f32x4 c) {
    return __builtin_amdgcn_mfma_f32_16x16x32_bf16(a, b, c, 0, 0, 0);
}
__device__ __forceinline__ void unpack8(uint4 v, float* f) {
    unsigned a0 = v.x, a1 = v.y, a2 = v.z, a3 = v.w;
    f[0] = bf2f((unsigned short)(a0 & 0xffff)); f[1] = bf2f((unsigned short)(a0 >> 16));
    f[2] = bf2f((unsigned short)(a1 & 0xffff)); f[3] = bf2f((unsigned short)(a1 >> 16));
    f[4] = bf2f((unsigned short)(a2 & 0xffff)); f[5] = bf2f((unsigned short)(a2 >> 16));
    f[6] = bf2f((unsigned short)(a3 & 0xffff)); f[7] = bf2f((unsigned short)(a3 >> 16));
}

// async global->LDS, 16B per lane; lds base wave-uniform, lanes land at base + lane*16
typedef const __attribute__((address_space(1))) unsigned int* as1_u32p;
typedef __attribute__((address_space(3))) unsigned int* as3_u32p;
__device__ __forceinline__ void gll16(const void* g, void* l) {
    __builtin_amdgcn_global_load_lds((as1_u32p)g, (as3_u32p)l, 16, 0, 0);
}

// ---------------- weight prep ----------------
// Wq (1024x512 f32), rows pre-scaled by LN gamma -> WqT bf16 [branch][512][1024]
__global__ void k_prep_wq(const float* __restrict__ wq1, const float* __restrict__ wq2,
                          const float* __restrict__ g1, const float* __restrict__ g2,
                          unsigned short* __restrict__ wqt) {
    __shared__ float tile[64][68];
    int bx = blockIdx.x, t = threadIdx.x;
    int br = bx >> 7, kt = (bx >> 3) & 15, nt = bx & 7;
    const float* wq = br ? wq2 : wq1;
    const float* gg = br ? g2 : g1;
#pragma unroll
    for (int i = 0; i < 4; ++i) {
        int idx4 = t + i * 256;
        int kl = idx4 >> 4, n4 = (idx4 & 15) * 4;
        float gv = gg[kt * 64 + kl];
        float4 v = *reinterpret_cast<const float4*>(wq + (size_t)(kt * 64 + kl) * 512 + nt * 64 + n4);
        tile[kl][n4 + 0] = v.x * gv; tile[kl][n4 + 1] = v.y * gv;
        tile[kl][n4 + 2] = v.z * gv; tile[kl][n4 + 3] = v.w * gv;
    }
    __syncthreads();
#pragma unroll
    for (int i = 0; i < 4; ++i) {
        int idx4 = t + i * 256;
        int nl = idx4 >> 4, k4 = (idx4 & 15) * 4;
        ushort4 o = make_ushort4(f2bf(tile[k4 + 0][nl]), f2bf(tile[k4 + 1][nl]),
                                 f2bf(tile[k4 + 2][nl]), f2bf(tile[k4 + 3][nl]));
        *reinterpret_cast<ushort4*>(wqt + (size_t)br * 512 * 1024 + (size_t)(nt * 64 + nl) * 1024 + kt * 64 + k4) = o;
    }
}

// qbias[br][e] = sum_d beta[d] * Wq[d][e]
__global__ void k_qbias(const float* __restrict__ wq1, const float* __restrict__ wq2,
                        const float* __restrict__ b1, const float* __restrict__ b2,
                        float* __restrict__ qbias) {
    int br = blockIdx.x >> 3, e0 = (blockIdx.x & 7) * 64;
    int t = threadIdx.x;
    int e = e0 + (t & 63), part = t >> 6;
    const float* wq = br ? wq2 : wq1;
    const float* bb = br ? b2 : b1;
    float s = 0.f;
    for (int d = part * 256; d < part * 256 + 256; ++d) s += bb[d] * wq[(size_t)d * 512 + e];
    __shared__ float red[256];
    red[t] = s;
    __syncthreads();
    if (t < 64) qbias[br * 512 + e0 + t] = red[t] + red[64 + t] + red[128 + t] + red[192 + t];
}

__global__ void k_f2bf(const float* __restrict__ src, unsigned short* __restrict__ dst, int n4) {
    int i = blockIdx.x * blockDim.x + threadIdx.x;
    if (i < n4) {
        float4 v = *reinterpret_cast<const float4*>(src + (size_t)i * 4);
        ushort4 o = make_ushort4(f2bf(v.x), f2bf(v.y), f2bf(v.z), f2bf(v.w));
        *reinterpret_cast<ushort4*>(dst + (size_t)i * 4) = o;
    }
}

// ---------------- kv layernorm:  text_fea (NT,B,TXT) -> kvn bf16 [b][n_pad1024][e] ----------------
__global__ void k_kvln(const float* __restrict__ tf, const float* __restrict__ g,
                       const float* __restrict__ bta, unsigned short* __restrict__ kvn) {
    int row = blockIdx.x;                 // b*1024 + n
    int b = row >> 10, n = row & 1023;
    int t = threadIdx.x;                  // 128 threads, 4 elems each
    unsigned short* dst = kvn + ((size_t)b * NTQ_ + n) * TXT_;
    if (n >= NT_) {                       // zero-pad rows
        *reinterpret_cast<ushort4*>(dst + t * 4) = make_ushort4(0, 0, 0, 0);
        return;
    }
    const float* src = tf + ((size_t)n * B_ + b) * TXT_;
    float4 v = *reinterpret_cast<const float4*>(src + t * 4);
    float s = v.x + v.y + v.z + v.w;
    float ss = v.x * v.x + v.y * v.y + v.z * v.z + v.w * v.w;
#pragma unroll
    for (int d = 1; d < 64; d <<= 1) { s += __shfl_xor(s, d); ss += __shfl_xor(ss, d); }
    __shared__ float red[4];
    if ((t & 63) == 0) { red[(t >> 6) * 2] = s; red[(t >> 6) * 2 + 1] = ss; }
    __syncthreads();
    s = red[0] + red[2]; ss = red[1] + red[3];
    float m = s * (1.f / TXT_);
    float rs = rsqrtf(ss * (1.f / TXT_) - m * m + 1e-5f);
    int d0 = t * 4;
    ushort4 o = make_ushort4(f2bf((v.x - m) * rs * g[d0 + 0] + bta[d0 + 0]),
                             f2bf((v.y - m) * rs * g[d0 + 1] + bta[d0 + 1]),
                             f2bf((v.z - m) * rs * g[d0 + 2] + bta[d0 + 2]),
                             f2bf((v.w - m) * rs * g[d0 + 3] + bta[d0 + 3]));
    *reinterpret_cast<ushort4*>(dst + d0) = o;
}

// ---------------- kv transpose:  kvn [b][n][e] -> kvt [b][e][n_pad1024] ----------------
__global__ void k_kvt(const unsigned short* __restrict__ kvn, unsigned short* __restrict__ kvt) {
    __shared__ unsigned short tile[64][68];
    int bx = blockIdx.x;
    int b = bx >> 7, rem = bx & 127, et = rem >> 4, nt = rem & 15;
    int t = threadIdx.x;
#pragma unroll
    for (int i = 0; i < 4; ++i) {
        int idx4 = t + i * 256;
        int nl = idx4 >> 4, e4 = (idx4 & 15) * 4;
        int ng = nt * 64 + nl;
        ushort4 v = make_ushort4(0, 0, 0, 0);
        if (ng < NT_) v = *reinterpret_cast<const ushort4*>(kvn + ((size_t)b * NTQ_ + ng) * TXT_ + et * 64 + e4);
        tile[nl][e4 + 0] = v.x; tile[nl][e4 + 1] = v.y; tile[nl][e4 + 2] = v.z; tile[nl][e4 + 3] = v.w;
    }
    __syncthreads();
#pragma unroll
    for (int i = 0; i < 4; ++i) {
        int idx4 = t + i * 256;
        int el = idx4 >> 4, n4 = (idx4 & 15) * 4;
        ushort4 o = make_ushort4(tile[n4 + 0][el], tile[n4 + 1][el], tile[n4 + 2][el], tile[n4 + 3][el]);
        *reinterpret_cast<ushort4*>(kvt + ((size_t)b * TXT_ + et * 64 + el) * NTP_ + nt * 64 + n4) = o;
    }
}

// ---------------- x layernorm (normalized only; gamma/beta folded into Wq) ----------------
__global__ void k_xln(const float* __restrict__ x, unsigned short* __restrict__ xn) {
    int bt = blockIdx.x;                   // b*TOK + t
    int b = bt / TOK_, tk = bt - b * TOK_;
    const float* src = x + ((size_t)(tk + 1) * B_ + b) * DIM_;
    int t = threadIdx.x;                   // 256 threads, 4 floats each
    float4 v = *reinterpret_cast<const float4*>(src + t * 4);
    float s = v.x + v.y + v.z + v.w;
    float ss = v.x * v.x + v.y * v.y + v.z * v.z + v.w * v.w;
#pragma unroll
    for (int d = 1; d < 64; d <<= 1) { s += __shfl_xor(s, d); ss += __shfl_xor(ss, d); }
    __shared__ float red[8];
    if ((t & 63) == 0) { red[t >> 6] = s; red[4 + (t >> 6)] = ss; }
    __syncthreads();
    s = red[0] + red[1] + red[2] + red[3];
    ss = red[4] + red[5] + red[6] + red[7];
    float m = s * (1.f / DIM_);
    float rs = rsqrtf(ss * (1.f / DIM_) - m * m + 1e-5f);
    int d0 = t * 4;
    ushort4 o = make_ushort4(f2bf((v.x - m) * rs), f2bf((v.y - m) * rs),
                             f2bf((v.z - m) * rs), f2bf((v.w - m) * rs));
    *reinterpret_cast<ushort4*>(xn + (size_t)bt * DIM_ + d0) = o;
}

// ---------------- 128x128xK bf16 GEMM mainloop, global_load_lds staging (m97 structure) ----------------
// A:[M][K], B:[N][K], both k-contiguous.
__device__ __forceinline__ void gemm_loop_gll(const unsigned short* __restrict__ A,
                                              const unsigned short* __restrict__ Bp,
                                              int K, unsigned short* a_lds, unsigned short* b_lds,
                                              int tid, f32x4 acc[4][4]) {
    const int l = tid & 63, w = tid >> 6;
    const int l16 = l & 15, lg = l >> 4;
    const int wm = w & 1, wn = w >> 1;
    const f32x4 fz = {0.f, 0.f, 0.f, 0.f};
#pragma unroll
    for (int mt = 0; mt < 4; ++mt)
#pragma unroll
        for (int nt = 0; nt < 4; ++nt) acc[mt][nt] = fz;
    const int lrow = l >> 3;               // 0..7
    const int k8g = (l & 7) ^ lrow;        // pre-swizzled source granule
    const int nk = K >> 6;
    for (int kt = 0; kt < nk; ++kt) {
#pragma unroll
        for (int i = 0; i < 4; ++i) {
            int row = i * 32 + w * 8 + lrow;
            gll16(A + (size_t)row * K + kt * 64 + k8g * 8, &a_lds[(i * 256 + w * 64) * 8]);
        }
#pragma unroll
        for (int i = 0; i < 4; ++i) {
            int row = i * 32 + w * 8 + lrow;
            gll16(Bp + (size_t)row * K + kt * 64 + k8g * 8, &b_lds[(i * 256 + w * 64) * 8]);
        }
        __syncthreads();
#pragma unroll
        for (int kk = 0; kk < 2; ++kk) {
            bf16x8 af[4], bff[4];
#pragma unroll
            for (int mt = 0; mt < 4; ++mt) {
                int row = wm * 64 + mt * 16 + l16;
                int gs = (kk * 4 + lg) ^ (row & 7);
                af[mt] = *reinterpret_cast<const bf16x8*>(a_lds + row * 64 + gs * 8);
            }
#pragma unroll
            for (int nt = 0; nt < 4; ++nt) {
                int row = wn * 64 + nt * 16 + l16;
                int gs = (kk * 4 + lg) ^ (row & 7);
                bff[nt] = *reinterpret_cast<const bf16x8*>(b_lds + row * 64 + gs * 8);
            }
#pragma unroll
            for (int mt = 0; mt < 4; ++mt)
#pragma unroll
                for (int nt = 0; nt < 4; ++nt)
                    acc[mt][nt] = mfma16(af[mt], bff[nt], acc[mt][nt]);
        }
        __syncthreads();
    }
}

// ---------------- 96x128xK variant (M-tile 96 keeps tiles inside one b: 576 = 6*96) ----------------
__device__ __forceinline__ void gemm_loop96(const unsigned short* __restrict__ A,
                                            const unsigned short* __restrict__ Bp,
                                            int K, unsigned short* a_lds, unsigned short* b_lds,
                                            int tid, f32x4 acc[3][4]) {
    const int l = tid & 63, w = tid >> 6;
    const int l16 = l & 15, lg = l >> 4;
    const int wm = w & 1, wn = w >> 1;
    const f32x4 fz = {0.f, 0.f, 0.f, 0.f};
#pragma unroll
    for (int mt = 0; mt < 3; ++mt)
#pragma unroll
        for (int nt = 0; nt < 4; ++nt) acc[mt][nt] = fz;
    const int lrow = l >> 3;
    const int k8g = (l & 7) ^ lrow;
    const int nk = K >> 6;
    for (int kt = 0; kt < nk; ++kt) {
#pragma unroll
        for (int i = 0; i < 3; ++i) {
            int row = i * 32 + w * 8 + lrow;
            gll16(A + (size_t)row * K + kt * 64 + k8g * 8, &a_lds[(i * 256 + w * 64) * 8]);
        }
#pragma unroll
        for (int i = 0; i < 4; ++i) {
            int row = i * 32 + w * 8 + lrow;
            gll16(Bp + (size_t)row * K + kt * 64 + k8g * 8, &b_lds[(i * 256 + w * 64) * 8]);
        }
        __syncthreads();
#pragma unroll
        for (int kk = 0; kk < 2; ++kk) {
            bf16x8 af[3], bff[4];
#pragma unroll
            for (int mt = 0; mt < 3; ++mt) {
                int row = wm * 48 + mt * 16 + l16;
                int gs = (kk * 4 + lg) ^ (row & 7);
                af[mt] = *reinterpret_cast<const bf16x8*>(a_lds + row * 64 + gs * 8);
            }
#pragma unroll
            for (int nt = 0; nt < 4; ++nt) {
                int row = wn * 64 + nt * 16 + l16;
                int gs = (kk * 4 + lg) ^ (row & 7);
                bff[nt] = *reinterpret_cast<const bf16x8*>(b_lds + row * 64 + gs * 8);
            }
#pragma unroll
            for (int mt = 0; mt < 3; ++mt)
#pragma unroll
                for (int nt = 0; nt < 4; ++nt)
                    acc[mt][nt] = mfma16(af[mt], bff[nt], acc[mt][nt]);
        }
        __syncthreads();
    }
}

// q GEMM:  q[br] = (xn @ (diag(g)Wq[br])^T + bias) * SCALE  -> bf16 (36864x512)
__global__ __launch_bounds__(256, 4) void k_qgemm(const unsigned short* __restrict__ xn,
                                                  const unsigned short* __restrict__ wqt,
                                                  const float* __restrict__ qbias,
                                                  unsigned short* __restrict__ qb) {
    int bid = blockIdx.x;                        // 2304 = 4bn x 288bm x 2br
    int vb = (bid & 7) * 288 + (bid >> 3);       // XCD-contiguous
    int bn = vb & 3;
    int t = vb >> 2;
    int br = (t >= 288) ? 1 : 0;
    int bm = t - br * 288;
    const unsigned short* A = xn + (size_t)bm * 128 * DIM_;
    const unsigned short* Bp = wqt + (size_t)br * 512 * 1024 + (size_t)bn * 128 * 1024;
    unsigned short* C = qb + (size_t)br * BT_ * TXT_;
    const float* bias = qbias + br * 512;
    __shared__ unsigned short a_lds[128 * 64];
    __shared__ unsigned short b_lds[128 * 64];
    f32x4 acc[4][4];
    gemm_loop_gll(A, Bp, DIM_, a_lds, b_lds, threadIdx.x, acc);
    const int l = threadIdx.x & 63, w = threadIdx.x >> 6;
    const int l16 = l & 15, lg = l >> 4, wm = w & 1, wn = w >> 1;
#pragma unroll
    for (int mt = 0; mt < 4; ++mt)
#pragma unroll
        for (int nt = 0; nt < 4; ++nt) {
            int col = bn * 128 + wn * 64 + nt * 16 + l16;
            float bv = bias[col];
#pragma unroll
            for (int r = 0; r < 4; ++r) {
                int row = bm * 128 + wm * 64 + mt * 16 + lg * 4 + r;
                C[(size_t)row * TXT_ + col] = f2bf((acc[mt][nt][r] + bv) * SCALE_);
            }
        }
}

// score GEMM: P = exp(q @ kvn^T) per branch, + row-sum atomics into denom
__global__ __launch_bounds__(256, 4) void k_score(const unsigned short* __restrict__ qbuf,
                                                  const unsigned short* __restrict__ kvn,
                                                  unsigned short* __restrict__ P,
                                                  float* __restrict__ denom, int br) {
    int bid = blockIdx.x;                        // 3072 = 64b x 6mt x 8nt
    int vb = (bid & 7) * 384 + (bid >> 3);       // XCD-contiguous, 8 b's per XCD
    int tile = vb % 48, b = vb / 48;
    int mt = tile >> 3, nt = tile & 7;
    const unsigned short* A = qbuf + ((size_t)br * BT_ + (size_t)b * TOK_ + mt * 96) * TXT_;
    const unsigned short* Bp = kvn + (size_t)b * NTQ_ * TXT_ + (size_t)nt * 128 * TXT_;
    __shared__ unsigned short a_lds[96 * 64];
    __shared__ unsigned short b_lds[128 * 64];
    f32x4 acc[3][4];
    gemm_loop96(A, Bp, TXT_, a_lds, b_lds, threadIdx.x, acc);
    const int l = threadIdx.x & 63, w = threadIdx.x >> 6;
    const int l16 = l & 15, lg = l >> 4, wm = w & 1, wn = w >> 1;
    float* dn = denom + (size_t)br * BT_;
#pragma unroll
    for (int mt2 = 0; mt2 < 3; ++mt2)
#pragma unroll
        for (int r = 0; r < 4; ++r) {
            int row = b * TOK_ + mt * 96 + wm * 48 + mt2 * 16 + lg * 4 + r;
            float s = 0.f;
#pragma unroll
            for (int nt2 = 0; nt2 < 4; ++nt2) {
                int col = nt * 128 + wn * 64 + nt2 * 16 + l16;
                float p = (col < NT_) ? __expf(acc[mt2][nt2][r]) : 0.f;
                s += p;
                P[(size_t)row * NTP_ + col] = f2bf(p);
            }
#pragma unroll
            for (int d = 1; d < 16; d <<= 1) s += __shfl_xor(s, d);
            if (l16 == 0) atomicAdd(&dn[row], s);
        }
}

// PV GEMM: O = (P @ kvt^T) / denom -> bf16
__global__ __launch_bounds__(256, 4) void k_pv(const unsigned short* __restrict__ P,
                                               const unsigned short* __restrict__ kvt,
                                               const float* __restrict__ denom,
                                               unsigned short* __restrict__ ob, int br) {
    int bid = blockIdx.x;                        // 1536 = 64b x 6mt x 4nt
    int vb = (bid & 7) * 192 + (bid >> 3);       // XCD-contiguous, 8 b's per XCD
    int tile = vb % 24, b = vb / 24;
    int mt = tile >> 2, nt = tile & 3;
    const unsigned short* A = P + ((size_t)b * TOK_ + mt * 96) * NTP_;
    const unsigned short* Bp = kvt + (size_t)b * TXT_ * NTP_ + (size_t)nt * 128 * NTP_;
    __shared__ unsigned short a_lds[96 * 64];
    __shared__ unsigned short b_lds[128 * 64];
    f32x4 acc[3][4];
    gemm_loop96(A, Bp, NTP_, a_lds, b_lds, threadIdx.x, acc);
    const int l = threadIdx.x & 63, w = threadIdx.x >> 6;
    const int l16 = l & 15, lg = l >> 4, wm = w & 1, wn = w >> 1;
    const float* dn = denom + (size_t)br * BT_;
#pragma unroll
    for (int mt2 = 0; mt2 < 3; ++mt2)
#pragma unroll
        for (int r = 0; r < 4; ++r) {
            int row = b * TOK_ + mt * 96 + wm * 48 + mt2 * 16 + lg * 4 + r;
            float inv = 1.f / dn[row];
            unsigned short* dst = ob + ((size_t)br * BT_ + row) * TXT_;
#pragma unroll
            for (int nt2 = 0; nt2 < 4; ++nt2) {
                int col = nt * 128 + wn * 64 + nt2 * 16 + l16;
                dst[col] = f2bf(acc[mt2][nt2][r] * inv);
            }
        }
}

// final GEMM: y = xse (36864x512) @ Wf^T (1024x512) -> fp32 scattered into out layout
__global__ __launch_bounds__(256, 4) void k_fgemm(const unsigned short* __restrict__ xse,
                                                  const unsigned short* __restrict__ wfb,
                                                  float* __restrict__ out) {
    int bid = blockIdx.x;                        // 2304 = 8bn x 288bm
    int vb = (bid & 7) * 288 + (bid >> 3);
    int bn = vb & 7, bm = vb >> 3;
    const unsigned short* A = xse + (size_t)bm * 128 * TXT_;
    const unsigned short* Bp = wfb + (size_t)bn * 128 * TXT_;
    __shared__ unsigned short a_lds[128 * 64];
    __shared__ unsigned short b_lds[128 * 64];
    f32x4 acc[4][4];
    gemm_loop_gll(A, Bp, TXT_, a_lds, b_lds, threadIdx.x, acc);
    const int l = threadIdx.x & 63, w = threadIdx.x >> 6;
    const int l16 = l & 15, lg = l >> 4, wm = w & 1, wn = w >> 1;
#pragma unroll
    for (int mt = 0; mt < 4; ++mt)
#pragma unroll
        for (int r = 0; r < 4; ++r) {
            int rowg = bm * 128 + wm * 64 + mt * 16 + lg * 4 + r;
            int b = rowg / TOK_, tk = rowg - b * TOK_;
            float* dst = out + ((size_t)(tk + 1) * B_ + b) * DIM_;
#pragma unroll
            for (int nt = 0; nt < 4; ++nt) {
                int col = bn * 128 + wn * 64 + nt * 16 + l16;
                dst[col] = acc[mt][nt][r];
            }
        }
}

// ---------------- channel mean (o1) / max (o2) per row ----------------
__global__ void k_avgmax(const unsigned short* __restrict__ o1, const unsigned short* __restrict__ o2,
                         float* __restrict__ avgb, float* __restrict__ maxb) {
    int row = blockIdx.x * 4 + (threadIdx.x >> 6);
    int l = threadIdx.x & 63;
    float f[8];
    unpack8(*reinterpret_cast<const uint4*>(o1 + (size_t)row * TXT_ + l * 8), f);
    float s = f[0] + f[1] + f[2] + f[3] + f[4] + f[5] + f[6] + f[7];
    unpack8(*reinterpret_cast<const uint4*>(o2 + (size_t)row * TXT_ + l * 8), f);
    float mx = f[0];
#pragma unroll
    for (int j = 1; j < 8; ++j) mx = fmaxf(mx, f[j]);
#pragma unroll
    for (int d = 1; d < 64; d <<= 1) { s += __shfl_xor(s, d); mx = fmaxf(mx, __shfl_xor(mx, d)); }
    if (l == 0) { avgb[row] = s * (1.f / TXT_); maxb[row] = mx; }
}

// ---------------- 3x3 depthwise conv on 24x24 + sigmoid gates ----------------
__global__ void k_gate(const float* __restrict__ avgb, const float* __restrict__ maxb,
                       const float* __restrict__ cdw, float* __restrict__ g1, float* __restrict__ g2) {
    int idx = blockIdx.x * 256 + threadIdx.x;     // < 36864
    int b = idx / TOK_, hw = idx - b * TOK_, h = hw / H_, ww = hw - h * H_;
    float a1 = 0.f, a2 = 0.f;
#pragma unroll
    for (int ky = 0; ky < 3; ++ky)
#pragma unroll
        for (int kx = 0; kx < 3; ++kx) {
            int hh = h + ky - 1, wx = ww + kx - 1;
            if (hh >= 0 && hh < H_ && wx >= 0 && wx < H_) {
                float wv = cdw[ky * 3 + kx];
                int s = b * TOK_ + hh * H_ + wx;
                a1 += wv * avgb[s];
                a2 += wv * maxb[s];
            }
        }
    g1[idx] = 1.f / (1.f + __expf(-a1));
    g2[idx] = 1.f / (1.f + __expf(-a2));
}

// ---------------- x_se = o1*g1 + o2*g2 -> bf16 ----------------
__global__ void k_xse(const unsigned short* __restrict__ o1, const unsigned short* __restrict__ o2,
                      const float* __restrict__ g1, const float* __restrict__ g2,
                      unsigned short* __restrict__ xse) {
    int idx8 = blockIdx.x * 256 + threadIdx.x;    // < 36864*64
    int bt = idx8 >> 6, e8 = idx8 & 63;
    float f1[8], f2[8];
    unpack8(*reinterpret_cast<const uint4*>(o1 + (size_t)bt * TXT_ + e8 * 8), f1);
    unpack8(*reinterpret_cast<const uint4*>(o2 + (size_t)bt * TXT_ + e8 * 8), f2);
    float gg1 = g1[bt], gg2 = g2[bt];
    unsigned r[4];
#pragma unroll
    for (int j = 0; j < 4; ++j) {
        unsigned lo = f2bf(f1[2 * j] * gg1 + f2[2 * j] * gg2);
        unsigned hi = f2bf(f1[2 * j + 1] * gg1 + f2[2 * j + 1] * gg2);
        r[j] = lo | (hi << 16);
    }
    uint4 o = make_uint4(r[0], r[1], r[2], r[3]);
    *reinterpret_cast<uint4*>(xse + (size_t)bt * TXT_ + e8 * 8) = o;
}

// ---------------- launcher ----------------
extern "C" void kernel_launch(void* const* d_in, const int* in_sizes, int n_in,
                              void* d_out, int out_size, void* d_ws, size_t ws_size,
                              hipStream_t stream) {
    (void)in_sizes; (void)n_in; (void)out_size; (void)ws_size;
    const float* x    = (const float*)d_in[0];
    const float* tf   = (const float*)d_in[1];
    const float* lq1g = (const float*)d_in[2];
    const float* lq1b = (const float*)d_in[3];
    const float* lq2g = (const float*)d_in[4];
    const float* lq2b = (const float*)d_in[5];
    const float* lkvg = (const float*)d_in[6];
    const float* lkvb = (const float*)d_in[7];
    const float* wq1  = (const float*)d_in[8];
    const float* wq2  = (const float*)d_in[9];
    const float* cdw  = (const float*)d_in[10];
    const float* wf   = (const float*)d_in[11];
    float* out = (float*)d_out;

    char* ws = (char*)d_ws;
    size_t off = 0;
    auto carve = [&](size_t bytes) { char* p = ws + off; off += (bytes + 255) & ~(size_t)255; return p; };
    unsigned short* kvn  = (unsigned short*)carve((size_t)B_ * NTQ_ * TXT_ * 2);       // 67.1 MB
    unsigned short* kvt  = (unsigned short*)carve((size_t)B_ * TXT_ * NTP_ * 2);       // 67.1 MB
    unsigned short* wqt  = (unsigned short*)carve((size_t)2 * 512 * 1024 * 2);         // 2 MB
    unsigned short* wfb  = (unsigned short*)carve((size_t)1024 * 512 * 2);             // 1 MB
    float* qbias = (float*)carve((size_t)2 * 512 * 4);
    float* denom = (float*)carve((size_t)2 * BT_ * 4);                                 // 0.3 MB
    float* avgb = (float*)carve((size_t)BT_ * 4);
    float* maxb = (float*)carve((size_t)BT_ * 4);
    float* g1v  = (float*)carve((size_t)BT_ * 4);
    float* g2v  = (float*)carve((size_t)BT_ * 4);
    unsigned short* xn   = (unsigned short*)carve((size_t)BT_ * DIM_ * 2);             // 75.5 MB
    unsigned short* qbuf = (unsigned short*)carve((size_t)2 * BT_ * TXT_ * 2);         // 75.5 MB
    unsigned short* ob   = (unsigned short*)carve((size_t)2 * BT_ * TXT_ * 2);         // 75.5 MB
    unsigned short* Pm   = xn;     // P (36864x1024 bf16, per branch): xn dead after k_qgemm
    unsigned short* xse  = qbuf;   // safe: qbuf dead after last k_score

    // row 0 of output = x_cls
    hipMemcpyAsync(out, x, (size_t)B_ * DIM_ * sizeof(float), hipMemcpyDeviceToDevice, stream);

    k_prep_wq<<<256, 256, 0, stream>>>(wq1, wq2, lq1g, lq2g, wqt);
    k_qbias<<<16, 256, 0, stream>>>(wq1, wq2, lq1b, lq2b, qbias);
    k_f2bf<<<512, 256, 0, stream>>>(wf, wfb, 131072);
    k_kvln<<<B_ * NTQ_, 128, 0, stream>>>(tf, lkvg, lkvb, kvn);
    k_kvt<<<8192, 256, 0, stream>>>(kvn, kvt);
    k_xln<<<BT_, 256, 0, stream>>>(x, xn);
    k_qgemm<<<2304, 256, 0, stream>>>(xn, wqt, qbias, qbuf);
    hipMemsetAsync(denom, 0, (size_t)2 * BT_ * 4, stream);
    // branch 0
    k_score<<<3072, 256, 0, stream>>>(qbuf, kvn, Pm, denom, 0);
    k_pv<<<1536, 256, 0, stream>>>(Pm, kvt, denom, ob, 0);
    // branch 1 (P buffer reused; stream-ordered)
    k_score<<<3072, 256, 0, stream>>>(qbuf, kvn, Pm, denom, 1);
    k_pv<<<1536, 256, 0, stream>>>(Pm, kvt, denom, ob, 1);
    k_avgmax<<<9216, 256, 0, stream>>>(ob, ob + (size_t)BT_ * TXT_, avgb, maxb);
    k_gate<<<144, 256, 0, stream>>>(avgb, maxb, cdw, g1v, g2v);
    k_xse<<<9216, 256, 0, stream>>>(ob, ob + (size_t)BT_ * TXT_, g1v, g2v, xse);
    k_fgemm<<<2304, 256, 0, stream>>>(xse, wfb, out);
}